// Round 8
// baseline (257.579 us; speedup 1.0000x reference)
//
#include <hip/hip_runtime.h>
#include <math.h>

// YOLOX loss, fixed shapes: B=32, A = 80*80 + 40*40 + 20*20 = 8400, 85 channels.
constexpr int A_TOTAL = 8400;
constexpr int AGPI    = A_TOTAL / 4;   // anchor-groups per image = 2100

// clang native vectors (real vector types -> clean dwordx4 codegen)
typedef float v4f __attribute__((ext_vector_type(4)));
typedef int   v4i __attribute__((ext_vector_type(4)));

__device__ __forceinline__ float bce(float x, float t) {
    // max(x,0) - x*t + softplus(-|x|); hw exp/log (v_exp_f32/v_log_f32)
    float ax = fabsf(x);
    float sp = __logf(1.0f + __expf(-ax));
    return fmaxf(x, 0.0f) - x * t + sp;
}

__device__ __forceinline__ v4f ld4(const float* p) {
    return *reinterpret_cast<const v4f*>(p);
}

// consume one chunk: 4 classes x 4 anchors; static indices only (rule #20)
__device__ __forceinline__ void consume_chunk(const v4f (&L)[4], const v4f (&T)[4],
                                              float& a0, float& a1, float& a2, float& a3) {
    #pragma unroll
    for (int c = 0; c < 4; ++c) {
        a0 += bce(L[c][0], T[0][c]);
        a1 += bce(L[c][1], T[1][c]);
        a2 += bce(L[c][2], T[2][c]);
        a3 += bce(L[c][3], T[3][c]);
    }
}

// Fused kernel. Thread layout: t = ag*4 + q.
//   ag = anchor group (4 consecutive anchors), q = class quarter (20 classes).
// Software-pipelined: 5 chunks of {4 logit float4 + 4 target float4},
// double-buffered so ~8 x 1KB loads stay in flight per wave.
__global__ __launch_bounds__(256, 4) void yolox_fused(
    const float* __restrict__ out0, const float* __restrict__ out1,
    const float* __restrict__ out2, const float* __restrict__ regt,
    const float* __restrict__ clst, const int* __restrict__ fgm,
    double* __restrict__ acc, int B)
{
    int t  = blockIdx.x * blockDim.x + threadIdx.x;
    int q  = t & 3;
    int ag = t >> 2;
    int b  = ag / AGPI;
    int rg = ag - b * AGPI;
    int a0i = rg * 4;                      // anchor index within image (mult of 4)

    const float* obase; int HW; float stride; int al; int W;
    if (a0i < 6400)      { obase = out0 + (size_t)b * 85 * 6400; HW = 6400; stride = 8.0f;  al = a0i;        W = 80; }
    else if (a0i < 8000) { obase = out1 + (size_t)b * 85 * 1600; HW = 1600; stride = 16.0f; al = a0i - 6400; W = 40; }
    else                 { obase = out2 + (size_t)b * 85 * 400;  HW = 400;  stride = 32.0f; al = a0i - 8000; W = 20; }

    const float* cb    = obase + (size_t)(5 + q * 20) * HW + al;          // cls logits
    const float* tbase = clst + ((size_t)b * A_TOTAL + a0i) * 80 + q * 20; // cls targets

    // ---- independent early loads: iou/obj/fg/regt stream ----
    int aa = al + q;                        // this thread's own anchor (local)
    float tx   = obase[aa];
    float ty   = obase[(size_t)1 * HW + aa];
    float tw   = obase[(size_t)2 * HW + aa];
    float th   = obase[(size_t)3 * HW + aa];
    float tobj = obase[(size_t)4 * HW + aa];
    v4f rt  = ld4(regt + ((size_t)b * A_TOTAL + a0i + q) * 4);
    v4i fg4 = *reinterpret_cast<const v4i*>(fgm + (size_t)b * A_TOTAL + a0i);

    // ---- pipelined cls BCE ----
    v4f L0[4], L1[4], T0[4], T1[4];
    #pragma unroll
    for (int i = 0; i < 4; ++i) L0[i] = ld4(cb + (size_t)i * HW);
    #pragma unroll
    for (int j = 0; j < 4; ++j) T0[j] = ld4(tbase + (size_t)j * 80);

    float s0 = 0.f, s1 = 0.f, s2 = 0.f, s3 = 0.f;

    #pragma unroll
    for (int k = 0; k < 5; ++k) {
        if (k < 4) {
            if ((k & 1) == 0) {
                #pragma unroll
                for (int i = 0; i < 4; ++i) L1[i] = ld4(cb + (size_t)(4 * (k + 1) + i) * HW);
                #pragma unroll
                for (int j = 0; j < 4; ++j) T1[j] = ld4(tbase + (size_t)j * 80 + 4 * (k + 1));
            } else {
                #pragma unroll
                for (int i = 0; i < 4; ++i) L0[i] = ld4(cb + (size_t)(4 * (k + 1) + i) * HW);
                #pragma unroll
                for (int j = 0; j < 4; ++j) T0[j] = ld4(tbase + (size_t)j * 80 + 4 * (k + 1));
            }
        }
        if ((k & 1) == 0) consume_chunk(L0, T0, s0, s1, s2, s3);
        else              consume_chunk(L1, T1, s0, s1, s2, s3);
    }

    float fgf0 = (float)fg4.x, fgf1 = (float)fg4.y, fgf2 = (float)fg4.z, fgf3 = (float)fg4.w;
    float local = s0 * fgf0 + s1 * fgf1 + s2 * fgf2 + s3 * fgf3;

    // ---- IoU + objectness for anchor a0i+q ----
    int gx = aa % W;
    int gy = aa / W;
    float px = (tx + (float)gx) * stride;
    float py = (ty + (float)gy) * stride;
    float pw = __expf(tw) * stride;
    float ph = __expf(th) * stride;

    float fgv = q == 0 ? fgf0 : (q == 1 ? fgf1 : (q == 2 ? fgf2 : fgf3));

    float tlx = fmaxf(px - pw * 0.5f, rt.x - rt.z * 0.5f);
    float tly = fmaxf(py - ph * 0.5f, rt.y - rt.w * 0.5f);
    float brx = fminf(px + pw * 0.5f, rt.x + rt.z * 0.5f);
    float bry = fminf(py + ph * 0.5f, rt.y + rt.w * 0.5f);
    float area_p = pw * ph;
    float area_g = rt.z * rt.w;
    float en = ((tlx < brx) && (tly < bry)) ? 1.0f : 0.0f;
    float area_i = (brx - tlx) * (bry - tly) * en;
    float area_u = area_p + area_g - area_i;
    float iou = area_i / (area_u + 1e-16f);
    float l_iou = 1.0f - iou * iou;

    local += 5.0f * l_iou * fgv + bce(tobj, fgv);
    float fgl = fgv;

    // ---- block reduction + atomics ----
    for (int off = 32; off > 0; off >>= 1) {
        local += __shfl_down(local, off, 64);
        fgl   += __shfl_down(fgl,   off, 64);
    }
    __shared__ float s_v[4], s_w[4];
    int wid  = threadIdx.x >> 6;
    int lane = threadIdx.x & 63;
    if (lane == 0) { s_v[wid] = local; s_w[wid] = fgl; }
    __syncthreads();
    if (threadIdx.x == 0) {
        atomicAdd(&acc[0], (double)(s_v[0] + s_v[1] + s_v[2] + s_v[3]));
        atomicAdd(&acc[1], (double)(s_w[0] + s_w[1] + s_w[2] + s_w[3]));
    }
}

__global__ void yolox_final(const double* __restrict__ acc, float* __restrict__ out) {
    out[0] = (float)(acc[0] / fmax(acc[1], 1.0));
}

extern "C" void kernel_launch(void* const* d_in, const int* in_sizes, int n_in,
                              void* d_out, int out_size, void* d_ws, size_t ws_size,
                              hipStream_t stream) {
    const float* out0 = (const float*)d_in[0];
    const float* out1 = (const float*)d_in[1];
    const float* out2 = (const float*)d_in[2];
    const float* regt = (const float*)d_in[3];
    const float* clst = (const float*)d_in[4];
    const int*   fgm  = (const int*)d_in[5];

    int B = in_sizes[0] / (85 * 6400);
    double* acc = (double*)d_ws;
    (void)hipMemsetAsync(acc, 0, 2 * sizeof(double), stream);

    int total  = B * A_TOTAL;                 // one thread per (anchor-group, quarter)
    int blocks = (total + 255) / 256;         // 1050 blocks for B=32
    hipLaunchKernelGGL(yolox_fused, dim3(blocks), dim3(256), 0, stream,
                       out0, out1, out2, regt, clst, fgm, acc, B);
    hipLaunchKernelGGL(yolox_final, dim3(1), dim3(1), 0, stream, acc, (float*)d_out);
}

// Round 9
// 209.450 us; speedup vs baseline: 1.2298x; 1.2298x over previous
//
#include <hip/hip_runtime.h>
#include <math.h>

// YOLOX loss, fixed shapes: B=32, A = 80*80 + 40*40 + 20*20 = 8400, 85 channels.
// Roofline note: irreducible logical reads = 183 MB; measured vector-load
// delivery ceiling on this rig ~2.5 TB/s -> ~73 us floor for the main kernel
// (R3/R4/R5/R7 all pinned at ~74 us across wildly different structures).
constexpr int A_TOTAL = 8400;
constexpr int AGPI    = A_TOTAL / 4;   // anchor-groups per image = 2100

typedef float v4f __attribute__((ext_vector_type(4)));
typedef int   v4i __attribute__((ext_vector_type(4)));

__device__ __forceinline__ float bce(float x, float t) {
    // max(x,0) - x*t + softplus(-|x|); hw exp/log (v_exp_f32/v_log_f32)
    float ax = fabsf(x);
    float sp = __logf(1.0f + __expf(-ax));
    return fmaxf(x, 0.0f) - x * t + sp;
}

__device__ __forceinline__ v4f ld4(const float* p) {
    return *reinterpret_cast<const v4f*>(p);
}

// Fused kernel (R5 structure — proven no-spill: VGPR 96, WRITE 65KB).
// Thread t -> q = t&3 (class quarter), ag = t>>2 (4 consecutive anchors).
// Each thread: cls BCE for 4 anchors x 20 classes + IoU/obj for anchor a0+q.
// Per-block partial sums written to d_ws (no global atomics).
__global__ __launch_bounds__(256) void yolox_fused(
    const float* __restrict__ out0, const float* __restrict__ out1,
    const float* __restrict__ out2, const float* __restrict__ regt,
    const float* __restrict__ clst, const int* __restrict__ fgm,
    float* __restrict__ partials, int B)
{
    int t  = blockIdx.x * blockDim.x + threadIdx.x;
    int q  = t & 3;
    int ag = t >> 2;
    int b  = ag / AGPI;
    int rg = ag - b * AGPI;
    int a0 = rg * 4;                       // anchor index within image (mult of 4)

    const float* obase; int HW; float stride; int al; int W;
    if (a0 < 6400)      { obase = out0 + (size_t)b * 85 * 6400; HW = 6400; stride = 8.0f;  al = a0;        W = 80; }
    else if (a0 < 8000) { obase = out1 + (size_t)b * 85 * 1600; HW = 1600; stride = 16.0f; al = a0 - 6400; W = 40; }
    else                { obase = out2 + (size_t)b * 85 * 400;  HW = 400;  stride = 32.0f; al = a0 - 8000; W = 20; }

    // ---- cls logits: 20 x float4 across 4 consecutive anchors (16B/lane) ----
    v4f L[20];
    const float* cb = obase + (size_t)(5 + q * 20) * HW + al;
    #pragma unroll
    for (int i = 0; i < 20; ++i)
        L[i] = ld4(cb + (size_t)i * HW);

    // fg for the 4 anchors (one int4)
    v4i fg4 = *reinterpret_cast<const v4i*>(fgm + (size_t)b * A_TOTAL + a0);
    float fgf[4] = { (float)fg4.x, (float)fg4.y, (float)fg4.z, (float)fg4.w };

    // ---- cls BCE: per anchor j, 20 classes ----
    float local = 0.0f;
    #pragma unroll
    for (int j = 0; j < 4; ++j) {
        const float* tp = clst + ((size_t)b * A_TOTAL + a0 + j) * 80 + q * 20;
        float tg[20];
        #pragma unroll
        for (int i5 = 0; i5 < 5; ++i5) {
            v4f tv = ld4(tp + 4 * i5);
            tg[4 * i5 + 0] = tv.x; tg[4 * i5 + 1] = tv.y;
            tg[4 * i5 + 2] = tv.z; tg[4 * i5 + 3] = tv.w;
        }
        float s = 0.0f;
        #pragma unroll
        for (int i = 0; i < 20; ++i)
            s += bce(L[i][j], tg[i]);
        local += s * fgf[j];
    }

    // ---- IoU + objectness for anchor a0+q ----
    int aa = al + q;                        // local anchor within level
    int gx = aa % W;
    int gy = aa / W;
    float tx   = obase[aa];
    float ty   = obase[(size_t)1 * HW + aa];
    float tw   = obase[(size_t)2 * HW + aa];
    float th   = obase[(size_t)3 * HW + aa];
    float tobj = obase[(size_t)4 * HW + aa];

    float px = (tx + (float)gx) * stride;
    float py = (ty + (float)gy) * stride;
    float pw = __expf(tw) * stride;
    float ph = __expf(th) * stride;

    v4f rt = ld4(regt + ((size_t)b * A_TOTAL + a0 + q) * 4);
    float fgv = fgf[q];

    float tlx = fmaxf(px - pw * 0.5f, rt.x - rt.z * 0.5f);
    float tly = fmaxf(py - ph * 0.5f, rt.y - rt.w * 0.5f);
    float brx = fminf(px + pw * 0.5f, rt.x + rt.z * 0.5f);
    float bry = fminf(py + ph * 0.5f, rt.y + rt.w * 0.5f);
    float area_p = pw * ph;
    float area_g = rt.z * rt.w;
    float en = ((tlx < brx) && (tly < bry)) ? 1.0f : 0.0f;
    float area_i = (brx - tlx) * (bry - tly) * en;
    float area_u = area_p + area_g - area_i;
    float iou = area_i / (area_u + 1e-16f);
    float l_iou = 1.0f - iou * iou;

    local += 5.0f * l_iou * fgv + bce(tobj, fgv);
    float fgl = fgv;

    // ---- block reduction -> per-block partial (no atomics) ----
    for (int off = 32; off > 0; off >>= 1) {
        local += __shfl_down(local, off, 64);
        fgl   += __shfl_down(fgl,   off, 64);
    }
    __shared__ float s_v[4], s_w[4];
    int wid  = threadIdx.x >> 6;
    int lane = threadIdx.x & 63;
    if (lane == 0) { s_v[wid] = local; s_w[wid] = fgl; }
    __syncthreads();
    if (threadIdx.x == 0) {
        partials[2 * blockIdx.x + 0] = s_v[0] + s_v[1] + s_v[2] + s_v[3];
        partials[2 * blockIdx.x + 1] = s_w[0] + s_w[1] + s_w[2] + s_w[3];
    }
}

// Final: single block reduces nblocks float2 partials (double accum).
__global__ __launch_bounds__(256) void yolox_final(
    const float* __restrict__ partials, float* __restrict__ out, int nblocks)
{
    double lsum = 0.0, fsum = 0.0;
    for (int i = threadIdx.x; i < nblocks; i += 256) {
        lsum += (double)partials[2 * i + 0];
        fsum += (double)partials[2 * i + 1];
    }
    for (int off = 32; off > 0; off >>= 1) {
        lsum += __shfl_down(lsum, off, 64);
        fsum += __shfl_down(fsum, off, 64);
    }
    __shared__ double d_v[4], d_w[4];
    int wid  = threadIdx.x >> 6;
    int lane = threadIdx.x & 63;
    if (lane == 0) { d_v[wid] = lsum; d_w[wid] = fsum; }
    __syncthreads();
    if (threadIdx.x == 0) {
        double l = d_v[0] + d_v[1] + d_v[2] + d_v[3];
        double f = d_w[0] + d_w[1] + d_w[2] + d_w[3];
        out[0] = (float)(l / fmax(f, 1.0));
    }
}

extern "C" void kernel_launch(void* const* d_in, const int* in_sizes, int n_in,
                              void* d_out, int out_size, void* d_ws, size_t ws_size,
                              hipStream_t stream) {
    const float* out0 = (const float*)d_in[0];
    const float* out1 = (const float*)d_in[1];
    const float* out2 = (const float*)d_in[2];
    const float* regt = (const float*)d_in[3];
    const float* clst = (const float*)d_in[4];
    const int*   fgm  = (const int*)d_in[5];

    int B = in_sizes[0] / (85 * 6400);
    float* partials = (float*)d_ws;           // 2 floats per block, written unconditionally

    int total  = B * A_TOTAL;                 // one thread per (anchor-group, quarter)
    int blocks = (total + 255) / 256;         // 1050 blocks for B=32 (exact)
    hipLaunchKernelGGL(yolox_fused, dim3(blocks), dim3(256), 0, stream,
                       out0, out1, out2, regt, clst, fgm, partials, B);
    hipLaunchKernelGGL(yolox_final, dim3(1), dim3(256), 0, stream,
                       partials, (float*)d_out, blocks);
}